// Round 7
// baseline (7726.361 us; speedup 1.0000x reference)
//
#include <hip/hip_runtime.h>
#include <hip/hip_bf16.h>

#define T_STEPS 4096
#define D_IN    512
#define F_DIM   256
#define HID     200
#define G4      800
#define KDIM    40
#define NSLOT   128

#define TPW    7
#define KT     7     // K tiles of 32 covering 200 (pad 224)
#define CH     16    // chunk size (steps)
#define NCHUNK 256   // 4096/16
#define NWORK  62    // gpre worker blocks

typedef _Float16 f16x8 __attribute__((ext_vector_type(8)));
typedef float    f32x4 __attribute__((ext_vector_type(4)));

// ---- dtype-mode helpers (mode 0 = f32 inputs, mode 1 = bf16 inputs) ----
__device__ __forceinline__ float ldin(const void* p, long i, int bf) {
  if (bf) {
    unsigned v = ((unsigned)((const unsigned short*)p)[i]) << 16;
    return __uint_as_float(v);
  }
  return ((const float*)p)[i];
}

__device__ __forceinline__ unsigned short f2bf(float x) {
  unsigned b = __float_as_uint(x);
  b = (b + 0x7FFFu + ((b >> 16) & 1u)) >> 16;
  return (unsigned short)b;
}

__device__ __forceinline__ float frcp(float x) { return __builtin_amdgcn_rcpf(x); }
__device__ __forceinline__ float frsq(float x) { return __builtin_amdgcn_rsqf(x); }

// DPP quad_perm shuffle: 1-cycle VALU lane exchange within each 4-lane quad
// (replaces __shfl_xor -> ds_bpermute, ~120 cyc LDS latency each).
// ctrl 0xB1 = [1,0,3,2] (xor 1), 0x4E = [2,3,0,1] (xor 2).
__device__ __forceinline__ float dppq_xor1(float x) {
  return __int_as_float(__builtin_amdgcn_update_dpp(
      0, __float_as_int(x), 0xB1, 0xF, 0xF, false));
}
__device__ __forceinline__ float dppq_xor2(float x) {
  return __int_as_float(__builtin_amdgcn_update_dpp(
      0, __float_as_int(x), 0x4E, 0xF, 0xF, false));
}

// async global->LDS, 16B per lane; dst wave-uniform base (linear fill)
__device__ __forceinline__ void gload_lds16(const float* g, float* lds) {
  __builtin_amdgcn_global_load_lds(
      (const __attribute__((address_space(1))) unsigned int*)g,
      (__attribute__((address_space(3))) unsigned int*)lds, 16, 0, 0);
}

// k-element map shared by A- and B-fragment fills (permutation-robust trick)
__device__ __forceinline__ int kmap(int grp, int e) {
  return (e < 4) ? (4 * grp + e) : (16 + 4 * grp + (e - 4));
}

// full-wave (64-lane) allreduce sum
__device__ __forceinline__ float wave_sum64(float v) {
  v += __int_as_float(__builtin_amdgcn_update_dpp(0, __float_as_int(v), 0x121, 0xF, 0xF, 0));
  v += __int_as_float(__builtin_amdgcn_update_dpp(0, __float_as_int(v), 0x122, 0xF, 0xF, 0));
  v += __int_as_float(__builtin_amdgcn_update_dpp(0, __float_as_int(v), 0x124, 0xF, 0xF, 0));
  v += __int_as_float(__builtin_amdgcn_update_dpp(0, __float_as_int(v), 0x128, 0xF, 0xF, 0));
  v += __int_as_float(__builtin_amdgcn_ds_swizzle(__float_as_int(v), 0x401F));
  v += __shfl_xor(v, 32, 64);
  return v;
}

// ---- producer/consumer flags (agent scope; relaxed poll + one acquire) ----
__device__ __forceinline__ void spin_flag(const unsigned* f) {
  if (__hip_atomic_load(f, __ATOMIC_RELAXED, __HIP_MEMORY_SCOPE_AGENT) == 0u) {
    while (__hip_atomic_load(f, __ATOMIC_RELAXED, __HIP_MEMORY_SCOPE_AGENT) == 0u)
      __builtin_amdgcn_s_sleep(2);
  }
  (void)__hip_atomic_load(f, __ATOMIC_ACQUIRE, __HIP_MEMORY_SCOPE_AGENT);
}
__device__ __forceinline__ void set_flag(unsigned* f) {
  __hip_atomic_store(f, 1u, __ATOMIC_RELEASE, __HIP_MEMORY_SCOPE_AGENT);
}

// ---- kernel 0: detect input dtype from gamma (== 0.95) ----
__global__ void detect_mode_k(const void* gamma, int* flag) {
  unsigned u32 = ((const unsigned*)gamma)[0];
  float asf  = __uint_as_float(u32);
  float asbf = __uint_as_float(((unsigned)((const unsigned short*)gamma)[0]) << 16);
  int m = 0;
  if (asf > 0.90f && asf < 1.0f) m = 0;
  else if (asbf > 0.90f && asbf < 1.0f) m = 1;
  *flag = m;
}

// ---- kernel 1: xs = x_train @ W_in + b_in   [4096,512]@[512,256] ----
__global__ __launch_bounds__(256) void xs_k(const void* x, const void* Win, const void* bin,
                                            float* xs, const int* flagp) {
  int bf = *flagp;
  int f = threadIdx.x;
  int t0 = blockIdx.x * 8;
  __shared__ float xl[8][D_IN];
  for (int idx = threadIdx.x; idx < 8 * D_IN; idx += 256)
    xl[idx >> 9][idx & 511] = ldin(x, (long)(t0 + (idx >> 9)) * D_IN + (idx & 511), bf);
  __syncthreads();
  float acc[8];
  float bv = ldin(bin, f, bf);
#pragma unroll
  for (int i = 0; i < 8; ++i) acc[i] = bv;
  for (int k = 0; k < D_IN; ++k) {
    float w = ldin(Win, (long)k * F_DIM + f, bf);
#pragma unroll
    for (int i = 0; i < 8; ++i) acc[i] += xl[i][k] * w;
  }
#pragma unroll
  for (int i = 0; i < 8; ++i) xs[(long)(t0 + i) * F_DIM + f] = acc[i];
}

// ---- fused producer/consumer kernel ----
// block 0: LSTM scan (needs gpre chunks; publishes hid chunks)
// block 1: keys + c2/c3 + MANN scan (consumes hid chunks; writes out)
// blocks 2..63: gpre workers (consume xs; publish gpre chunks)
struct SmemLstm {
  float gbuf[2][CH][G4];          // 102,400 B
  float hh[2][CH][HID];           //  25,600 B
  _Float16 h_fr[2][224];          //     896 B
};
struct SmemWork {
  float xl[CH][F_DIM];            //  16,384 B
  float yl[CH];
};
struct SmemCons {
  float WkT[KDIM][HID];           //  32,000 B
  float Wsl[HID];                 //     800 B
  float hl[CH][HID];              //  12,800 B
  float rc[CH][96];               //   6,144 B
};
union SmemU { SmemLstm l; SmemWork w; SmemCons c; };

__global__ __launch_bounds__(512, 1) void fused_k(
    const void* Whh, const void* Wih, const void* bih, const void* bhh,
    const void* y, const float* xs,
    const void* Wk, const void* bk, const void* Ws, const void* bs,
    float* gpre, float* hid, void* out,
    unsigned* fg, unsigned* fh, const int* flagp) {
  __shared__ SmemU sm;
  int bf = *flagp;
  int bid = blockIdx.x;
  int tid = threadIdx.x;

  if (bid >= 2) {
    // ================= gpre worker =================
    for (int c = bid - 2; c < NCHUNK; c += NWORK) {
      int t0 = c * CH;
      for (int i = tid; i < CH * F_DIM / 4; i += 512)
        ((float4*)sm.w.xl)[i] = ((const float4*)(xs + (long)t0 * F_DIM))[i];
      if (tid < CH) {
        int t = t0 + tid;
        sm.w.yl[tid] = (t == 0) ? 0.f : ldin(y, t - 1, bf);
      }
      __syncthreads();
      for (int j = tid; j < G4; j += 512) {
        int gate = j / 200, unit = j - gate * 200;
        int jv = 4 * unit + gate;          // interleaved virtual row
        float base = ldin(bih, j, bf) + ldin(bhh, j, bf);
        float acc[CH];
#pragma unroll
        for (int s = 0; s < CH; ++s) acc[s] = base;
        for (int f4 = 0; f4 < F_DIM / 4; ++f4) {
          float w0 = ldin(Wih, (long)j * 257 + 4 * f4 + 0, bf);
          float w1 = ldin(Wih, (long)j * 257 + 4 * f4 + 1, bf);
          float w2 = ldin(Wih, (long)j * 257 + 4 * f4 + 2, bf);
          float w3 = ldin(Wih, (long)j * 257 + 4 * f4 + 3, bf);
#pragma unroll
          for (int s = 0; s < CH; ++s) {
            float4 xv = *((const float4*)sm.w.xl[s] + f4);
            acc[s] = fmaf(xv.x, w0, acc[s]);
            acc[s] = fmaf(xv.y, w1, acc[s]);
            acc[s] = fmaf(xv.z, w2, acc[s]);
            acc[s] = fmaf(xv.w, w3, acc[s]);
          }
        }
        float wy = ldin(Wih, (long)j * 257 + 256, bf);
#pragma unroll
        for (int s = 0; s < CH; ++s)
          gpre[(long)(t0 + s) * G4 + jv] = fmaf(sm.w.yl[s], wy, acc[s]);
      }
      __syncthreads();                 // drains all threads' stores
      if (tid == 0) set_flag(&fg[c]);
    }
    return;
  }

  if (bid == 1) {
    // ================= consumer: keys + c23 + MANN =================
    for (int i = tid; i < KDIM * HID; i += 512) {
      int kk = i / HID, u = i - kk * HID;
      ((float*)sm.c.WkT)[i] = ldin(Wk, (long)u * KDIM + kk, bf);
    }
    for (int i = tid; i < HID; i += 512) sm.c.Wsl[i] = ldin(Ws, i, bf);
    __syncthreads();

    float M0[KDIM], M1[KDIM];
#pragma unroll
    for (int q = 0; q < KDIM; ++q) { M0[q] = 1e-6f; M1[q] = 1e-6f; }
    float nsq0 = 4.0e-11f, nsq1 = 4.0e-11f;
    float wr0 = (tid == 0) ? 1.f : 0.f, wr1 = 0.f;

    for (int c = 0; c < NCHUNK; ++c) {
      spin_flag(&fh[c]);
      for (int i = tid; i < CH * HID / 4; i += 512)
        ((float4*)sm.c.hl)[i] = ((const float4*)(hid + (long)c * CH * HID))[i];
      __syncthreads();   // A: hl ready; also: prev-chunk mann (wave0) done

      // keys / sigma: 656 tasks (s, kk)
      for (int task = tid; task < CH * 41; task += 512) {
        int s = task / 41, kk = task - s * 41;
        const float4* hp = (const float4*)sm.c.hl[s];
        if (kk < KDIM) {
          float acc = ldin(bk, kk, bf);
          const float4* wp = (const float4*)sm.c.WkT[kk];
#pragma unroll
          for (int u4 = 0; u4 < HID / 4; ++u4) {
            float4 hv = hp[u4], wv = wp[u4];
            acc = fmaf(hv.x, wv.x, acc);
            acc = fmaf(hv.y, wv.y, acc);
            acc = fmaf(hv.z, wv.z, acc);
            acc = fmaf(hv.w, wv.w, acc);
          }
          float kv = tanhf(acc);
          float kn = kv / fmaxf(fabsf(kv), 1e-12f);
          sm.c.rc[s][kk] = kv;
          sm.c.rc[s][KDIM + kk] = kn;
        } else {
          float acc = ldin(bs, 0, bf);
          const float4* wp = (const float4*)sm.c.Wsl;
#pragma unroll
          for (int u4 = 0; u4 < HID / 4; ++u4) {
            float4 hv = hp[u4], wv = wp[u4];
            acc = fmaf(hv.x, wv.x, acc);
            acc = fmaf(hv.y, wv.y, acc);
            acc = fmaf(hv.z, wv.z, acc);
            acc = fmaf(hv.w, wv.w, acc);
          }
          sm.c.rc[s][80] = 1.f / (1.f + expf(-acc));
        }
      }
      __syncthreads();   // B: keys ready
      if (tid < CH) {
        const float4* rp = (const float4*)sm.c.rc[tid];
        float c2 = 0.f, c3 = 0.f;
#pragma unroll
        for (int q = 0; q < 10; ++q) {
          float4 kv = rp[q], kn = rp[10 + q];
          c2 = fmaf(kv.x, kn.x, c2); c2 = fmaf(kv.y, kn.y, c2);
          c2 = fmaf(kv.z, kn.z, c2); c2 = fmaf(kv.w, kn.w, c2);
          c3 = fmaf(kv.x, kv.x, c3); c3 = fmaf(kv.y, kv.y, c3);
          c3 = fmaf(kv.z, kv.z, c3); c3 = fmaf(kv.w, kv.w, c3);
        }
        sm.c.rc[tid][81] = c2;
        sm.c.rc[tid][82] = c3;
        sm.c.rc[tid][83] = 0.f;
      }
      __syncthreads();   // C: rc complete

      if (tid < 64) {    // single-wave MANN: rows (tid, tid+64)
        for (int s = 0; s < CH; ++s) {
          const float4* rp = (const float4*)sm.c.rc[s];
          float4 ex = rp[20];                 // {sig, c2, c3, 0}
          float sg = ex.x;
          float ww0 = fmaf(sg, wr0, 1.f - sg);   // wlu == 1 identically
          float ww1 = fmaf(sg, wr1, 1.f - sg);
          float4 a0 = {0,0,0,0}, b0 = {0,0,0,0}, a1 = {0,0,0,0}, b1 = {0,0,0,0};
#pragma unroll
          for (int q = 0; q < 10; ++q) {
            float4 kv = rp[q], kn = rp[10 + q];
            float m00 = M0[4*q+0], m01 = M0[4*q+1], m02 = M0[4*q+2], m03 = M0[4*q+3];
            float m10 = M1[4*q+0], m11 = M1[4*q+1], m12 = M1[4*q+2], m13 = M1[4*q+3];
            a0.x = fmaf(m00, kn.x, a0.x); a0.y = fmaf(m01, kn.y, a0.y);
            a0.z = fmaf(m02, kn.z, a0.z); a0.w = fmaf(m03, kn.w, a0.w);
            b0.x = fmaf(m00, kv.x, b0.x); b0.y = fmaf(m01, kv.y, b0.y);
            b0.z = fmaf(m02, kv.z, b0.z); b0.w = fmaf(m03, kv.w, b0.w);
            a1.x = fmaf(m10, kn.x, a1.x); a1.y = fmaf(m11, kn.y, a1.y);
            a1.z = fmaf(m12, kn.z, a1.z); a1.w = fmaf(m13, kn.w, a1.w);
            b1.x = fmaf(m10, kv.x, b1.x); b1.y = fmaf(m11, kv.y, b1.y);
            b1.z = fmaf(m12, kv.z, b1.z); b1.w = fmaf(m13, kv.w, b1.w);
            M0[4*q+0] = fmaf(ww0, kv.x, m00); M0[4*q+1] = fmaf(ww0, kv.y, m01);
            M0[4*q+2] = fmaf(ww0, kv.z, m02); M0[4*q+3] = fmaf(ww0, kv.w, m03);
            M1[4*q+0] = fmaf(ww1, kv.x, m10); M1[4*q+1] = fmaf(ww1, kv.y, m11);
            M1[4*q+2] = fmaf(ww1, kv.z, m12); M1[4*q+3] = fmaf(ww1, kv.w, m13);
          }
          float D10 = (a0.x + a0.y) + (a0.z + a0.w);
          float D20 = (b0.x + b0.y) + (b0.z + b0.w);
          float D11 = (a1.x + a1.y) + (a1.z + a1.w);
          float D21 = (b1.x + b1.y) + (b1.z + b1.w);
          if ((s & 7) == 7) {                 // exact nsq refresh
            float4 r0 = {0,0,0,0}, r1 = {0,0,0,0};
#pragma unroll
            for (int q = 0; q < 10; ++q) {
              r0.x = fmaf(M0[4*q+0], M0[4*q+0], r0.x);
              r0.y = fmaf(M0[4*q+1], M0[4*q+1], r0.y);
              r0.z = fmaf(M0[4*q+2], M0[4*q+2], r0.z);
              r0.w = fmaf(M0[4*q+3], M0[4*q+3], r0.w);
              r1.x = fmaf(M1[4*q+0], M1[4*q+0], r1.x);
              r1.y = fmaf(M1[4*q+1], M1[4*q+1], r1.y);
              r1.z = fmaf(M1[4*q+2], M1[4*q+2], r1.z);
              r1.w = fmaf(M1[4*q+3], M1[4*q+3], r1.w);
            }
            nsq0 = (r0.x + r0.y) + (r0.z + r0.w);
            nsq1 = (r1.x + r1.y) + (r1.z + r1.w);
          } else {
            nsq0 = fmaf(ww0 * ww0, ex.z, fmaf(2.f * ww0, D20, nsq0));
            nsq1 = fmaf(ww1 * ww1, ex.z, fmaf(2.f * ww1, D21, nsq1));
          }
          float dot0 = fmaf(ww0, ex.y, D10);
          float dot1 = fmaf(ww1, ex.y, D11);
          float v0 = dot0 * frsq(fmaxf(nsq0, 1e-24f));
          float v1 = dot1 * frsq(fmaxf(nsq1, 1e-24f));
          float e0 = __expf(v0), e1 = __expf(v1);
          float es = wave_sum64(e0 + e1);
          float ri = frcp(es);
          wr0 = e0 * ri;
          wr1 = e1 * ri;
        }
      }
    }
    if (tid < 64) {
#pragma unroll
      for (int q = 0; q < KDIM; ++q) {
        long i0 = (long)tid * KDIM + q;
        long i1 = (long)(tid + 64) * KDIM + q;
        if (bf) {
          ((unsigned short*)out)[i0] = f2bf(M0[q]);
          ((unsigned short*)out)[i1] = f2bf(M1[q]);
        } else {
          ((float*)out)[i0] = M0[q];
          ((float*)out)[i1] = M1[q];
        }
      }
    }
    return;
  }

  // ================= LSTM scan (block 0) =================
  int lane = tid & 63, wid = tid >> 6;          // 8 waves
  int col = lane & 15, grp = (lane >> 4) & 3;
  int g = col & 3;        // gate of this lane's column
  int qq = col >> 2;      // unit-within-tile quad

  for (int i = tid; i < 448; i += 512) ((_Float16*)sm.l.h_fr)[i] = (_Float16)0.f;

  bool isg2 = (g == 2);
  float sx = isg2 ? 2.f : -1.f;
  float am = isg2 ? -2.f : 1.f;
  float ab = isg2 ? 1.f : 0.f;

  // B fragments: wave owns tiles t = wid + 8*it, it=0..6 (196 regs, AGPR-resident)
  f16x8 fB[TPW][KT];
#pragma unroll
  for (int it = 0; it < TPW; ++it) {
    int t = wid + 8 * it;
    bool ok = (t < 50);
    int u = 4 * t + qq;
    long rowbase = (long)(200 * g + (ok ? u : 0)) * HID;
#pragma unroll
    for (int kt = 0; kt < KT; ++kt) {
      f16x8 v;
#pragma unroll
      for (int e = 0; e < 8; ++e) {
        int k = kt * 32 + kmap(grp, e);
        float w = (ok && k < HID) ? ldin(Whh, rowbase + k, bf) : 0.f;
        v[e] = (_Float16)w;
      }
      fB[it][kt] = v;
    }
  }

  int t0_ = wid + 8 * grp;
  int t1_ = wid + 32 + 8 * grp;
  bool val1 = (grp < 3) && (t1_ < 50);
  int u0 = 4 * t0_ + qq, u1 = val1 ? (4 * t1_ + qq) : 0;
  int vv0 = 16 * t0_ + col;
  int vv1 = val1 ? (16 * t1_ + col) : 0;
  int pos0, pos1;
  {
    int r = u0 & 31;
    pos0 = (u0 >> 5) * 32 + ((r < 16) ? ((r >> 2) * 8 + (r & 3))
                                      : (((r - 16) >> 2) * 8 + 4 + ((r - 16) & 3)));
    r = u1 & 31;
    pos1 = (u1 >> 5) * 32 + ((r < 16) ? ((r >> 2) * 8 + (r & 3))
                                      : (((r - 16) >> 2) * 8 + 4 + ((r - 16) & 3)));
  }
  bool wrt = (g == 0);
  bool w2 = (wid < 2);

  // stage chunk 0 (wait for workers)
  spin_flag(&fg[0]);
  {
    float* dst = (float*)sm.l.gbuf[0];
    for (int sl = wid; sl < 50; sl += 8)
      gload_lds16(gpre + sl * 256 + lane * 4, dst + sl * 256);
  }
  __syncthreads();

  float cst0 = 0.f, cst1 = 0.f;
  int p = 0;
  for (int tc = 0; tc < T_STEPS; tc += CH) {
    int pb = (tc >> 4) & 1;
    int cn = tc / CH + 1;
    if (cn < NCHUNK) {
      spin_flag(&fg[cn]);
      const float* src = gpre + (long)(tc + CH) * G4;
      float* dst = (float*)sm.l.gbuf[pb ^ 1];
      for (int sl = wid; sl < 50; sl += 8)
        gload_lds16(src + sl * 256 + lane * 4, dst + sl * 256);
    }
    for (int s = 0; s < CH; ++s) {
      // ---- issue all LDS reads first (latency hides under MFMA issue) ----
      f16x8 a7[KT];
#pragma unroll
      for (int kt = 0; kt < KT; ++kt)
        a7[kt] = *(const f16x8*)&sm.l.h_fr[p][kt * 32 + grp * 8];
      float gb0 = sm.l.gbuf[pb][s][vv0];
      float gb1 = sm.l.gbuf[pb][s][vv1];

      // ---- split-depth MFMA chains: lo = kt 0-3, hi = kt 4-6 ----
      f32x4 lo[TPW], hi[TPW];
#pragma unroll
      for (int i = 0; i < TPW; ++i) { lo[i] = (f32x4){0,0,0,0}; hi[i] = (f32x4){0,0,0,0}; }
#pragma unroll
      for (int kt = 0; kt < 4; ++kt) {
        f16x8 a = a7[kt];
        lo[0] = __builtin_amdgcn_mfma_f32_16x16x32_f16(a, fB[0][kt], lo[0], 0, 0, 0);
        lo[1] = __builtin_amdgcn_mfma_f32_16x16x32_f16(a, fB[1][kt], lo[1], 0, 0, 0);
        lo[2] = __builtin_amdgcn_mfma_f32_16x16x32_f16(a, fB[2][kt], lo[2], 0, 0, 0);
        lo[3] = __builtin_amdgcn_mfma_f32_16x16x32_f16(a, fB[3][kt], lo[3], 0, 0, 0);
        lo[4] = __builtin_amdgcn_mfma_f32_16x16x32_f16(a, fB[4][kt], lo[4], 0, 0, 0);
        lo[5] = __builtin_amdgcn_mfma_f32_16x16x32_f16(a, fB[5][kt], lo[5], 0, 0, 0);
      }
#pragma unroll
      for (int kt = 4; kt < 7; ++kt) {
        f16x8 a = a7[kt];
        hi[0] = __builtin_amdgcn_mfma_f32_16x16x32_f16(a, fB[0][kt], hi[0], 0, 0, 0);
        hi[1] = __builtin_amdgcn_mfma_f32_16x16x32_f16(a, fB[1][kt], hi[1], 0, 0, 0);
        hi[2] = __builtin_amdgcn_mfma_f32_16x16x32_f16(a, fB[2][kt], hi[2], 0, 0, 0);
        hi[3] = __builtin_amdgcn_mfma_f32_16x16x32_f16(a, fB[3][kt], hi[3], 0, 0, 0);
        hi[4] = __builtin_amdgcn_mfma_f32_16x16x32_f16(a, fB[4][kt], hi[4], 0, 0, 0);
        hi[5] = __builtin_amdgcn_mfma_f32_16x16x32_f16(a, fB[5][kt], hi[5], 0, 0, 0);
      }
      if (w2) {                      // pad-skip: tile wid+48 only real for wid<2
#pragma unroll
        for (int kt = 0; kt < 4; ++kt)
          lo[6] = __builtin_amdgcn_mfma_f32_16x16x32_f16(a7[kt], fB[6][kt], lo[6], 0, 0, 0);
#pragma unroll
        for (int kt = 4; kt < 7; ++kt)
          hi[6] = __builtin_amdgcn_mfma_f32_16x16x32_f16(a7[kt], fB[6][kt], hi[6], 0, 0, 0);
      }
      float pj0 = lo[0][0] + hi[0][0];
      float pj1 = lo[1][0] + hi[1][0];
      float pj2 = lo[2][0] + hi[2][0];
      float pj3 = lo[3][0] + hi[3][0];
      float pj4 = lo[4][0] + hi[4][0];
      float pj5 = lo[5][0] + hi[5][0];
      float pj6 = lo[6][0] + hi[6][0];
      float pj_r0 = (grp == 0) ? pj0 : (grp == 1) ? pj1 : (grp == 2) ? pj2 : pj3;
      float pj_r1 = (grp == 0) ? pj4 : (grp == 1) ? pj5 : pj6;

      // ---- act round 0 (DPP quad shuffles) ----
      {
        float pre = pj_r0 + gb0;
        float yv = __expf(sx * pre);
        float z = frcp(1.f + yv);
        float act = fmaf(am, z, ab);
        float s1 = dppq_xor1(act);
        float a_e = (g & 1) ? s1 : act;
        float a_o = (g & 1) ? act : s1;
        float b_e = dppq_xor2(a_e);
        float b_o = dppq_xor2(a_o);
        float si = (g & 2) ? b_e : a_e;
        float sf = (g & 2) ? b_o : a_o;
        float tg = (g & 2) ? a_e : b_e;
        float so = (g & 2) ? a_o : b_o;
        float c = fmaf(sf, cst0, si * tg);
        cst0 = c;
        float th = 1.f - 2.f * frcp(1.f + __expf(2.f * c));
        float h = so * th;
        if (wrt) {
          sm.l.h_fr[p ^ 1][pos0] = (_Float16)h;
          sm.l.hh[pb][s][u0] = h;
        }
      }
      // ---- act round 1 (guarded writes) ----
      {
        float pre = pj_r1 + gb1;
        float yv = __expf(sx * pre);
        float z = frcp(1.f + yv);
        float act = fmaf(am, z, ab);
        float s1 = dppq_xor1(act);
        float a_e = (g & 1) ? s1 : act;
        float a_o = (g & 1) ? act : s1;
        float b_e = dppq_xor2(a_e);
        float b_o = dppq_xor2(a_o);
        float si = (g & 2) ? b_e : a_e;
        float sf = (g & 2) ? b_o : a_o;
        float tg = (g & 2) ? a_e : b_e;
        float so = (g & 2) ? a_o : b_o;
        float c = fmaf(sf, cst1, si * tg);
        cst1 = c;
        float th = 1.f - 2.f * frcp(1.f + __expf(2.f * c));
        float h = so * th;
        if (wrt && val1) {
          sm.l.h_fr[p ^ 1][pos1] = (_Float16)h;
          sm.l.hh[pb][s][u1] = h;
        }
      }
      __syncthreads();
      p ^= 1;
    }
    // flush hid chunk, then publish
    {
      const float4* src = (const float4*)sm.l.hh[pb];
      float4* dst = (float4*)(hid + (long)tc * HID);
      for (int i = tid; i < CH * HID / 4; i += 512) dst[i] = src[i];
    }
    __syncthreads();
    if (tid == 0) set_flag(&fh[tc / CH]);
  }
}

extern "C" void kernel_launch(void* const* d_in, const int* in_sizes, int n_in,
                              void* d_out, int out_size, void* d_ws, size_t ws_size,
                              hipStream_t stream) {
  const void* x_train = d_in[0];
  const void* y_train = d_in[1];
  const void* W_in = d_in[2];
  const void* b_in = d_in[3];
  const void* W_ih = d_in[4];
  const void* W_hh = d_in[5];
  const void* b_ih = d_in[6];
  const void* b_hh = d_in[7];
  const void* W_k  = d_in[8];
  const void* b_k  = d_in[9];
  const void* W_s  = d_in[10];
  const void* b_s  = d_in[11];
  const void* gamma = d_in[12];

  char* ws = (char*)d_ws;
  int*      flag = (int*)ws;                         // +0      (4 B)
  unsigned* fg   = (unsigned*)(ws + 256);            // +256    (1024 B)
  unsigned* fh   = (unsigned*)(ws + 1280);           // +1280   (1024 B)
  float*    gpre = (float*)(ws + 4096);              // 13,107,200 B
  float*    hid  = (float*)(ws + 4096 + 13107200L);  //  3,276,800 B
  float*    xs   = (float*)(ws + 4096 + 13107200L + 3276800L);  // 4,194,304 B

  detect_mode_k<<<1, 1, 0, stream>>>(gamma, flag);
  hipMemsetAsync(ws + 256, 0, 2048, stream);
  xs_k<<<512, 256, 0, stream>>>(x_train, W_in, b_in, xs, flag);
  fused_k<<<64, 512, 0, stream>>>(W_hh, W_ih, b_ih, b_hh, y_train, xs,
                                  W_k, b_k, W_s, b_s,
                                  gpre, hid, d_out, fg, fh, flag);
}

// Round 8
// 5281.601 us; speedup vs baseline: 1.4629x; 1.4629x over previous
//
#include <hip/hip_runtime.h>
#include <hip/hip_bf16.h>

#define T_STEPS 4096
#define D_IN    512
#define F_DIM   256
#define HID     200
#define G4      800
#define KDIM    40
#define NSLOT   128

#define TPW    7
#define KT     7     // K tiles of 32 covering 200 (pad 224)
#define CH     16    // chunk size (steps)
#define NCHUNK 256   // 4096/16
#define NWORK  62    // gpre worker blocks

typedef _Float16 f16x8 __attribute__((ext_vector_type(8)));
typedef float    f32x4 __attribute__((ext_vector_type(4)));

// ---- dtype-mode helpers (mode 0 = f32 inputs, mode 1 = bf16 inputs) ----
__device__ __forceinline__ float ldin(const void* p, long i, int bf) {
  if (bf) {
    unsigned v = ((unsigned)((const unsigned short*)p)[i]) << 16;
    return __uint_as_float(v);
  }
  return ((const float*)p)[i];
}

__device__ __forceinline__ unsigned short f2bf(float x) {
  unsigned b = __float_as_uint(x);
  b = (b + 0x7FFFu + ((b >> 16) & 1u)) >> 16;
  return (unsigned short)b;
}

__device__ __forceinline__ float frcp(float x) { return __builtin_amdgcn_rcpf(x); }
__device__ __forceinline__ float frsq(float x) { return __builtin_amdgcn_rsqf(x); }

// DPP quad_perm shuffle: 1-cycle VALU lane exchange within each 4-lane quad
// (replaces __shfl_xor -> ds_bpermute, ~120 cyc LDS latency each).
// ctrl 0xB1 = [1,0,3,2] (xor 1), 0x4E = [2,3,0,1] (xor 2).
__device__ __forceinline__ float dppq_xor1(float x) {
  return __int_as_float(__builtin_amdgcn_update_dpp(
      0, __float_as_int(x), 0xB1, 0xF, 0xF, false));
}
__device__ __forceinline__ float dppq_xor2(float x) {
  return __int_as_float(__builtin_amdgcn_update_dpp(
      0, __float_as_int(x), 0x4E, 0xF, 0xF, false));
}

// async global->LDS, 16B per lane; dst wave-uniform base (linear fill)
__device__ __forceinline__ void gload_lds16(const float* g, float* lds) {
  __builtin_amdgcn_global_load_lds(
      (const __attribute__((address_space(1))) unsigned int*)g,
      (__attribute__((address_space(3))) unsigned int*)lds, 16, 0, 0);
}

// k-element map shared by A- and B-fragment fills (permutation-robust trick)
__device__ __forceinline__ int kmap(int grp, int e) {
  return (e < 4) ? (4 * grp + e) : (16 + 4 * grp + (e - 4));
}

// full-wave (64-lane) allreduce sum
__device__ __forceinline__ float wave_sum64(float v) {
  v += __int_as_float(__builtin_amdgcn_update_dpp(0, __float_as_int(v), 0x121, 0xF, 0xF, 0));
  v += __int_as_float(__builtin_amdgcn_update_dpp(0, __float_as_int(v), 0x122, 0xF, 0xF, 0));
  v += __int_as_float(__builtin_amdgcn_update_dpp(0, __float_as_int(v), 0x124, 0xF, 0xF, 0));
  v += __int_as_float(__builtin_amdgcn_update_dpp(0, __float_as_int(v), 0x128, 0xF, 0xF, 0));
  v += __int_as_float(__builtin_amdgcn_ds_swizzle(__float_as_int(v), 0x401F));
  v += __shfl_xor(v, 32, 64);
  return v;
}

// ---- producer/consumer flags (agent scope; relaxed poll + one acquire) ----
__device__ __forceinline__ void spin_flag(const unsigned* f) {
  if (__hip_atomic_load(f, __ATOMIC_RELAXED, __HIP_MEMORY_SCOPE_AGENT) == 0u) {
    while (__hip_atomic_load(f, __ATOMIC_RELAXED, __HIP_MEMORY_SCOPE_AGENT) == 0u)
      __builtin_amdgcn_s_sleep(2);
  }
  (void)__hip_atomic_load(f, __ATOMIC_ACQUIRE, __HIP_MEMORY_SCOPE_AGENT);
}
__device__ __forceinline__ void set_flag(unsigned* f) {
  __hip_atomic_store(f, 1u, __ATOMIC_RELEASE, __HIP_MEMORY_SCOPE_AGENT);
}

// ---- kernel 0: detect input dtype from gamma (== 0.95) ----
__global__ void detect_mode_k(const void* gamma, int* flag) {
  unsigned u32 = ((const unsigned*)gamma)[0];
  float asf  = __uint_as_float(u32);
  float asbf = __uint_as_float(((unsigned)((const unsigned short*)gamma)[0]) << 16);
  int m = 0;
  if (asf > 0.90f && asf < 1.0f) m = 0;
  else if (asbf > 0.90f && asbf < 1.0f) m = 1;
  *flag = m;
}

// ---- kernel 1: xs = x_train @ W_in + b_in   [4096,512]@[512,256] ----
__global__ __launch_bounds__(256) void xs_k(const void* x, const void* Win, const void* bin,
                                            float* xs, const int* flagp) {
  int bf = *flagp;
  int f = threadIdx.x;
  int t0 = blockIdx.x * 8;
  __shared__ float xl[8][D_IN];
  for (int idx = threadIdx.x; idx < 8 * D_IN; idx += 256)
    xl[idx >> 9][idx & 511] = ldin(x, (long)(t0 + (idx >> 9)) * D_IN + (idx & 511), bf);
  __syncthreads();
  float acc[8];
  float bv = ldin(bin, f, bf);
#pragma unroll
  for (int i = 0; i < 8; ++i) acc[i] = bv;
  for (int k = 0; k < D_IN; ++k) {
    float w = ldin(Win, (long)k * F_DIM + f, bf);
#pragma unroll
    for (int i = 0; i < 8; ++i) acc[i] += xl[i][k] * w;
  }
#pragma unroll
  for (int i = 0; i < 8; ++i) xs[(long)(t0 + i) * F_DIM + f] = acc[i];
}

// ---- fused producer/consumer kernel ----
// block 0: LSTM scan (needs gpre chunks; publishes hid chunks)
// block 1: keys + c2/c3 + MANN scan (consumes hid chunks; writes out)
// blocks 2..63: gpre workers (consume xs; publish gpre chunks)
struct SmemLstm {
  float gbuf[2][CH][G4];          // 102,400 B
  float hh[2][CH][HID];           //  25,600 B
  _Float16 h_fr[2][224];          //     896 B
};
struct SmemWork {
  float xl[CH][F_DIM];            //  16,384 B
  float yl[CH];
};
struct SmemCons {
  float WkT[KDIM][HID];           //  32,000 B
  float Wsl[HID];                 //     800 B
  float hl[CH][HID];              //  12,800 B
  float rc[CH][96];               //   6,144 B
};
union SmemU { SmemLstm l; SmemWork w; SmemCons c; };

__global__ __launch_bounds__(512, 2) void fused_k(
    const void* Whh, const void* Wih, const void* bih, const void* bhh,
    const void* y, const float* xs,
    const void* Wk, const void* bk, const void* Ws, const void* bs,
    float* gpre, float* hid, void* out,
    unsigned* fg, unsigned* fh, const int* flagp) {
  __shared__ SmemU sm;
  int bf = *flagp;
  int bid = blockIdx.x;
  int tid = threadIdx.x;

  if (bid >= 2) {
    // ================= gpre worker =================
    for (int c = bid - 2; c < NCHUNK; c += NWORK) {
      int t0 = c * CH;
      for (int i = tid; i < CH * F_DIM / 4; i += 512)
        ((float4*)sm.w.xl)[i] = ((const float4*)(xs + (long)t0 * F_DIM))[i];
      if (tid < CH) {
        int t = t0 + tid;
        sm.w.yl[tid] = (t == 0) ? 0.f : ldin(y, t - 1, bf);
      }
      __syncthreads();
      for (int j = tid; j < G4; j += 512) {
        int gate = j / 200, unit = j - gate * 200;
        int jv = 4 * unit + gate;          // interleaved virtual row
        float base = ldin(bih, j, bf) + ldin(bhh, j, bf);
        float acc[CH];
#pragma unroll
        for (int s = 0; s < CH; ++s) acc[s] = base;
        for (int f4 = 0; f4 < F_DIM / 4; ++f4) {
          float w0 = ldin(Wih, (long)j * 257 + 4 * f4 + 0, bf);
          float w1 = ldin(Wih, (long)j * 257 + 4 * f4 + 1, bf);
          float w2 = ldin(Wih, (long)j * 257 + 4 * f4 + 2, bf);
          float w3 = ldin(Wih, (long)j * 257 + 4 * f4 + 3, bf);
#pragma unroll
          for (int s = 0; s < CH; ++s) {
            float4 xv = *((const float4*)sm.w.xl[s] + f4);
            acc[s] = fmaf(xv.x, w0, acc[s]);
            acc[s] = fmaf(xv.y, w1, acc[s]);
            acc[s] = fmaf(xv.z, w2, acc[s]);
            acc[s] = fmaf(xv.w, w3, acc[s]);
          }
        }
        float wy = ldin(Wih, (long)j * 257 + 256, bf);
#pragma unroll
        for (int s = 0; s < CH; ++s)
          gpre[(long)(t0 + s) * G4 + jv] = fmaf(sm.w.yl[s], wy, acc[s]);
      }
      __syncthreads();                 // drains all threads' stores
      if (tid == 0) set_flag(&fg[c]);
    }
    return;
  }

  if (bid == 1) {
    // ================= consumer: keys + c23 + MANN =================
    for (int i = tid; i < KDIM * HID; i += 512) {
      int kk = i / HID, u = i - kk * HID;
      ((float*)sm.c.WkT)[i] = ldin(Wk, (long)u * KDIM + kk, bf);
    }
    for (int i = tid; i < HID; i += 512) sm.c.Wsl[i] = ldin(Ws, i, bf);
    __syncthreads();

    float M0[KDIM], M1[KDIM];
#pragma unroll
    for (int q = 0; q < KDIM; ++q) { M0[q] = 1e-6f; M1[q] = 1e-6f; }
    float nsq0 = 4.0e-11f, nsq1 = 4.0e-11f;
    float wr0 = (tid == 0) ? 1.f : 0.f, wr1 = 0.f;

    for (int c = 0; c < NCHUNK; ++c) {
      spin_flag(&fh[c]);
      for (int i = tid; i < CH * HID / 4; i += 512)
        ((float4*)sm.c.hl)[i] = ((const float4*)(hid + (long)c * CH * HID))[i];
      __syncthreads();   // A: hl ready; also: prev-chunk mann (wave0) done

      // keys / sigma: 656 tasks (s, kk)
      for (int task = tid; task < CH * 41; task += 512) {
        int s = task / 41, kk = task - s * 41;
        const float4* hp = (const float4*)sm.c.hl[s];
        if (kk < KDIM) {
          float acc = ldin(bk, kk, bf);
          const float4* wp = (const float4*)sm.c.WkT[kk];
#pragma unroll
          for (int u4 = 0; u4 < HID / 4; ++u4) {
            float4 hv = hp[u4], wv = wp[u4];
            acc = fmaf(hv.x, wv.x, acc);
            acc = fmaf(hv.y, wv.y, acc);
            acc = fmaf(hv.z, wv.z, acc);
            acc = fmaf(hv.w, wv.w, acc);
          }
          float kv = tanhf(acc);
          float kn = kv / fmaxf(fabsf(kv), 1e-12f);
          sm.c.rc[s][kk] = kv;
          sm.c.rc[s][KDIM + kk] = kn;
        } else {
          float acc = ldin(bs, 0, bf);
          const float4* wp = (const float4*)sm.c.Wsl;
#pragma unroll
          for (int u4 = 0; u4 < HID / 4; ++u4) {
            float4 hv = hp[u4], wv = wp[u4];
            acc = fmaf(hv.x, wv.x, acc);
            acc = fmaf(hv.y, wv.y, acc);
            acc = fmaf(hv.z, wv.z, acc);
            acc = fmaf(hv.w, wv.w, acc);
          }
          sm.c.rc[s][80] = 1.f / (1.f + expf(-acc));
        }
      }
      __syncthreads();   // B: keys ready
      if (tid < CH) {
        const float4* rp = (const float4*)sm.c.rc[tid];
        float c2 = 0.f, c3 = 0.f;
#pragma unroll
        for (int q = 0; q < 10; ++q) {
          float4 kv = rp[q], kn = rp[10 + q];
          c2 = fmaf(kv.x, kn.x, c2); c2 = fmaf(kv.y, kn.y, c2);
          c2 = fmaf(kv.z, kn.z, c2); c2 = fmaf(kv.w, kn.w, c2);
          c3 = fmaf(kv.x, kv.x, c3); c3 = fmaf(kv.y, kv.y, c3);
          c3 = fmaf(kv.z, kv.z, c3); c3 = fmaf(kv.w, kv.w, c3);
        }
        sm.c.rc[tid][81] = c2;
        sm.c.rc[tid][82] = c3;
        sm.c.rc[tid][83] = 0.f;
      }
      __syncthreads();   // C: rc complete

      if (tid < 64) {    // single-wave MANN: rows (tid, tid+64)
        for (int s = 0; s < CH; ++s) {
          const float4* rp = (const float4*)sm.c.rc[s];
          float4 ex = rp[20];                 // {sig, c2, c3, 0}
          float sg = ex.x;
          float ww0 = fmaf(sg, wr0, 1.f - sg);   // wlu == 1 identically
          float ww1 = fmaf(sg, wr1, 1.f - sg);
          float4 a0 = {0,0,0,0}, b0 = {0,0,0,0}, a1 = {0,0,0,0}, b1 = {0,0,0,0};
#pragma unroll
          for (int q = 0; q < 10; ++q) {
            float4 kv = rp[q], kn = rp[10 + q];
            float m00 = M0[4*q+0], m01 = M0[4*q+1], m02 = M0[4*q+2], m03 = M0[4*q+3];
            float m10 = M1[4*q+0], m11 = M1[4*q+1], m12 = M1[4*q+2], m13 = M1[4*q+3];
            a0.x = fmaf(m00, kn.x, a0.x); a0.y = fmaf(m01, kn.y, a0.y);
            a0.z = fmaf(m02, kn.z, a0.z); a0.w = fmaf(m03, kn.w, a0.w);
            b0.x = fmaf(m00, kv.x, b0.x); b0.y = fmaf(m01, kv.y, b0.y);
            b0.z = fmaf(m02, kv.z, b0.z); b0.w = fmaf(m03, kv.w, b0.w);
            a1.x = fmaf(m10, kn.x, a1.x); a1.y = fmaf(m11, kn.y, a1.y);
            a1.z = fmaf(m12, kn.z, a1.z); a1.w = fmaf(m13, kn.w, a1.w);
            b1.x = fmaf(m10, kv.x, b1.x); b1.y = fmaf(m11, kv.y, b1.y);
            b1.z = fmaf(m12, kv.z, b1.z); b1.w = fmaf(m13, kv.w, b1.w);
            M0[4*q+0] = fmaf(ww0, kv.x, m00); M0[4*q+1] = fmaf(ww0, kv.y, m01);
            M0[4*q+2] = fmaf(ww0, kv.z, m02); M0[4*q+3] = fmaf(ww0, kv.w, m03);
            M1[4*q+0] = fmaf(ww1, kv.x, m10); M1[4*q+1] = fmaf(ww1, kv.y, m11);
            M1[4*q+2] = fmaf(ww1, kv.z, m12); M1[4*q+3] = fmaf(ww1, kv.w, m13);
          }
          float D10 = (a0.x + a0.y) + (a0.z + a0.w);
          float D20 = (b0.x + b0.y) + (b0.z + b0.w);
          float D11 = (a1.x + a1.y) + (a1.z + a1.w);
          float D21 = (b1.x + b1.y) + (b1.z + b1.w);
          if ((s & 7) == 7) {                 // exact nsq refresh
            float4 r0 = {0,0,0,0}, r1 = {0,0,0,0};
#pragma unroll
            for (int q = 0; q < 10; ++q) {
              r0.x = fmaf(M0[4*q+0], M0[4*q+0], r0.x);
              r0.y = fmaf(M0[4*q+1], M0[4*q+1], r0.y);
              r0.z = fmaf(M0[4*q+2], M0[4*q+2], r0.z);
              r0.w = fmaf(M0[4*q+3], M0[4*q+3], r0.w);
              r1.x = fmaf(M1[4*q+0], M1[4*q+0], r1.x);
              r1.y = fmaf(M1[4*q+1], M1[4*q+1], r1.y);
              r1.z = fmaf(M1[4*q+2], M1[4*q+2], r1.z);
              r1.w = fmaf(M1[4*q+3], M1[4*q+3], r1.w);
            }
            nsq0 = (r0.x + r0.y) + (r0.z + r0.w);
            nsq1 = (r1.x + r1.y) + (r1.z + r1.w);
          } else {
            nsq0 = fmaf(ww0 * ww0, ex.z, fmaf(2.f * ww0, D20, nsq0));
            nsq1 = fmaf(ww1 * ww1, ex.z, fmaf(2.f * ww1, D21, nsq1));
          }
          float dot0 = fmaf(ww0, ex.y, D10);
          float dot1 = fmaf(ww1, ex.y, D11);
          float v0 = dot0 * frsq(fmaxf(nsq0, 1e-24f));
          float v1 = dot1 * frsq(fmaxf(nsq1, 1e-24f));
          float e0 = __expf(v0), e1 = __expf(v1);
          float es = wave_sum64(e0 + e1);
          float ri = frcp(es);
          wr0 = e0 * ri;
          wr1 = e1 * ri;
        }
      }
    }
    if (tid < 64) {
#pragma unroll
      for (int q = 0; q < KDIM; ++q) {
        long i0 = (long)tid * KDIM + q;
        long i1 = (long)(tid + 64) * KDIM + q;
        if (bf) {
          ((unsigned short*)out)[i0] = f2bf(M0[q]);
          ((unsigned short*)out)[i1] = f2bf(M1[q]);
        } else {
          ((float*)out)[i0] = M0[q];
          ((float*)out)[i1] = M1[q];
        }
      }
    }
    return;
  }

  // ================= LSTM scan (block 0) =================
  int lane = tid & 63, wid = tid >> 6;          // 8 waves
  int col = lane & 15, grp = (lane >> 4) & 3;
  int g = col & 3;        // gate of this lane's column
  int qq = col >> 2;      // unit-within-tile quad

  for (int i = tid; i < 448; i += 512) ((_Float16*)sm.l.h_fr)[i] = (_Float16)0.f;

  bool isg2 = (g == 2);
  float sx = isg2 ? 2.f : -1.f;
  float am = isg2 ? -2.f : 1.f;
  float ab = isg2 ? 1.f : 0.f;

  // B fragments: wave owns tiles t = wid + 8*it, it=0..6 (196 regs)
  f16x8 fB[TPW][KT];
#pragma unroll
  for (int it = 0; it < TPW; ++it) {
    int t = wid + 8 * it;
    bool ok = (t < 50);
    int u = 4 * t + qq;
    long rowbase = (long)(200 * g + (ok ? u : 0)) * HID;
#pragma unroll
    for (int kt = 0; kt < KT; ++kt) {
      f16x8 v;
#pragma unroll
      for (int e = 0; e < 8; ++e) {
        int k = kt * 32 + kmap(grp, e);
        float w = (ok && k < HID) ? ldin(Whh, rowbase + k, bf) : 0.f;
        v[e] = (_Float16)w;
      }
      fB[it][kt] = v;
    }
  }

  int t0_ = wid + 8 * grp;
  int t1_ = wid + 32 + 8 * grp;
  bool val1 = (grp < 3) && (t1_ < 50);
  int u0 = 4 * t0_ + qq, u1 = val1 ? (4 * t1_ + qq) : 0;
  int vv0 = 16 * t0_ + col;
  int vv1 = val1 ? (16 * t1_ + col) : 0;
  int pos0, pos1;
  {
    int r = u0 & 31;
    pos0 = (u0 >> 5) * 32 + ((r < 16) ? ((r >> 2) * 8 + (r & 3))
                                      : (((r - 16) >> 2) * 8 + 4 + ((r - 16) & 3)));
    r = u1 & 31;
    pos1 = (u1 >> 5) * 32 + ((r < 16) ? ((r >> 2) * 8 + (r & 3))
                                      : (((r - 16) >> 2) * 8 + 4 + ((r - 16) & 3)));
  }
  bool wrt = (g == 0);
  bool w2 = (wid < 2);

  // stage chunk 0 (wait for workers)
  spin_flag(&fg[0]);
  {
    float* dst = (float*)sm.l.gbuf[0];
    for (int sl = wid; sl < 50; sl += 8)
      gload_lds16(gpre + sl * 256 + lane * 4, dst + sl * 256);
  }
  __syncthreads();

  float cst0 = 0.f, cst1 = 0.f;
  int p = 0;
  for (int tc = 0; tc < T_STEPS; tc += CH) {
    int pb = (tc >> 4) & 1;
    int cn = tc / CH + 1;
    if (cn < NCHUNK) {
      spin_flag(&fg[cn]);
      const float* src = gpre + (long)(tc + CH) * G4;
      float* dst = (float*)sm.l.gbuf[pb ^ 1];
      for (int sl = wid; sl < 50; sl += 8)
        gload_lds16(src + sl * 256 + lane * 4, dst + sl * 256);
    }
    for (int s = 0; s < CH; ++s) {
      // ---- issue all LDS reads first (latency hides under MFMA issue) ----
      f16x8 a7[KT];
#pragma unroll
      for (int kt = 0; kt < KT; ++kt)
        a7[kt] = *(const f16x8*)&sm.l.h_fr[p][kt * 32 + grp * 8];
      float gb0 = sm.l.gbuf[pb][s][vv0];
      float gb1 = sm.l.gbuf[pb][s][vv1];

      // ---- kt-outer MFMA: 7 independent chains, one acc set (28 regs) ----
      f32x4 ac0 = {0,0,0,0}, ac1 = {0,0,0,0}, ac2 = {0,0,0,0}, ac3 = {0,0,0,0};
      f32x4 ac4 = {0,0,0,0}, ac5 = {0,0,0,0}, ac6 = {0,0,0,0};
#pragma unroll
      for (int kt = 0; kt < KT; ++kt) {
        f16x8 a = a7[kt];
        ac0 = __builtin_amdgcn_mfma_f32_16x16x32_f16(a, fB[0][kt], ac0, 0, 0, 0);
        ac1 = __builtin_amdgcn_mfma_f32_16x16x32_f16(a, fB[1][kt], ac1, 0, 0, 0);
        ac2 = __builtin_amdgcn_mfma_f32_16x16x32_f16(a, fB[2][kt], ac2, 0, 0, 0);
        ac3 = __builtin_amdgcn_mfma_f32_16x16x32_f16(a, fB[3][kt], ac3, 0, 0, 0);
        ac4 = __builtin_amdgcn_mfma_f32_16x16x32_f16(a, fB[4][kt], ac4, 0, 0, 0);
        ac5 = __builtin_amdgcn_mfma_f32_16x16x32_f16(a, fB[5][kt], ac5, 0, 0, 0);
      }
      if (w2) {                      // pad-skip: tile wid+48 only real for wid<2
#pragma unroll
        for (int kt = 0; kt < KT; ++kt)
          ac6 = __builtin_amdgcn_mfma_f32_16x16x32_f16(a7[kt], fB[6][kt], ac6, 0, 0, 0);
      }
      float pj_r0 = (grp == 0) ? ac0[0] : (grp == 1) ? ac1[0] : (grp == 2) ? ac2[0] : ac3[0];
      float pj_r1 = (grp == 0) ? ac4[0] : (grp == 1) ? ac5[0] : ac6[0];

      // ---- act round 0 (DPP quad shuffles) ----
      {
        float pre = pj_r0 + gb0;
        float yv = __expf(sx * pre);
        float z = frcp(1.f + yv);
        float act = fmaf(am, z, ab);
        float s1 = dppq_xor1(act);
        float a_e = (g & 1) ? s1 : act;
        float a_o = (g & 1) ? act : s1;
        float b_e = dppq_xor2(a_e);
        float b_o = dppq_xor2(a_o);
        float si = (g & 2) ? b_e : a_e;
        float sf = (g & 2) ? b_o : a_o;
        float tg = (g & 2) ? a_e : b_e;
        float so = (g & 2) ? a_o : b_o;
        float c = fmaf(sf, cst0, si * tg);
        cst0 = c;
        float th = 1.f - 2.f * frcp(1.f + __expf(2.f * c));
        float h = so * th;
        if (wrt) {
          sm.l.h_fr[p ^ 1][pos0] = (_Float16)h;
          sm.l.hh[pb][s][u0] = h;
        }
      }
      // ---- act round 1 (guarded writes) ----
      {
        float pre = pj_r1 + gb1;
        float yv = __expf(sx * pre);
        float z = frcp(1.f + yv);
        float act = fmaf(am, z, ab);
        float s1 = dppq_xor1(act);
        float a_e = (g & 1) ? s1 : act;
        float a_o = (g & 1) ? act : s1;
        float b_e = dppq_xor2(a_e);
        float b_o = dppq_xor2(a_o);
        float si = (g & 2) ? b_e : a_e;
        float sf = (g & 2) ? b_o : a_o;
        float tg = (g & 2) ? a_e : b_e;
        float so = (g & 2) ? a_o : b_o;
        float c = fmaf(sf, cst1, si * tg);
        cst1 = c;
        float th = 1.f - 2.f * frcp(1.f + __expf(2.f * c));
        float h = so * th;
        if (wrt && val1) {
          sm.l.h_fr[p ^ 1][pos1] = (_Float16)h;
          sm.l.hh[pb][s][u1] = h;
        }
      }
      __syncthreads();
      p ^= 1;
    }
    // flush hid chunk, then publish
    {
      const float4* src = (const float4*)sm.l.hh[pb];
      float4* dst = (float4*)(hid + (long)tc * HID);
      for (int i = tid; i < CH * HID / 4; i += 512) dst[i] = src[i];
    }
    __syncthreads();
    if (tid == 0) set_flag(&fh[tc / CH]);
  }
}

extern "C" void kernel_launch(void* const* d_in, const int* in_sizes, int n_in,
                              void* d_out, int out_size, void* d_ws, size_t ws_size,
                              hipStream_t stream) {
  const void* x_train = d_in[0];
  const void* y_train = d_in[1];
  const void* W_in = d_in[2];
  const void* b_in = d_in[3];
  const void* W_ih = d_in[4];
  const void* W_hh = d_in[5];
  const void* b_ih = d_in[6];
  const void* b_hh = d_in[7];
  const void* W_k  = d_in[8];
  const void* b_k  = d_in[9];
  const void* W_s  = d_in[10];
  const void* b_s  = d_in[11];
  const void* gamma = d_in[12];

  char* ws = (char*)d_ws;
  int*      flag = (int*)ws;                         // +0      (4 B)
  unsigned* fg   = (unsigned*)(ws + 256);            // +256    (1024 B)
  unsigned* fh   = (unsigned*)(ws + 1280);           // +1280   (1024 B)
  float*    gpre = (float*)(ws + 4096);              // 13,107,200 B
  float*    hid  = (float*)(ws + 4096 + 13107200L);  //  3,276,800 B
  float*    xs   = (float*)(ws + 4096 + 13107200L + 3276800L);  // 4,194,304 B

  detect_mode_k<<<1, 1, 0, stream>>>(gamma, flag);
  hipMemsetAsync(ws + 256, 0, 2048, stream);
  xs_k<<<512, 256, 0, stream>>>(x_train, W_in, b_in, xs, flag);
  fused_k<<<64, 512, 0, stream>>>(W_hh, W_ih, b_ih, b_hh, y_train, xs,
                                  W_k, b_k, W_s, b_s,
                                  gpre, hid, d_out, fg, fh, flag);
}